// Round 4
// baseline (158.964 us; speedup 1.0000x reference)
//
#include <hip/hip_runtime.h>
#include <cstdint>
#include <cstddef>

#define N_SEQ 4096
#define D_HEAD 128
#define KP_DIM 256

typedef __attribute__((ext_vector_type(4))) float f32x4;
typedef __attribute__((ext_vector_type(8))) short bf16x8;
typedef __attribute__((ext_vector_type(4))) short s16x4;
typedef __attribute__((ext_vector_type(2))) unsigned int u32x2;

static __device__ __forceinline__ short f2bf(float f) {
  uint32_t u = __builtin_bit_cast(uint32_t, f);
  u += 0x7FFFu + ((u >> 16) & 1u);
  return (short)(u >> 16);
}

static __device__ __forceinline__ unsigned int cvtpk(float a, float b) {
  unsigned int r;
  asm("v_cvt_pk_bf16_f32 %0, %1, %2" : "=v"(r) : "v"(a), "v"(b));
  return r;
}

static __device__ __forceinline__ int swz8(int r) { return (r ^ (r >> 2)) & 7; }

// ---------------------------------------------------------------------------
// Stage 0: convert E_W,F_W f32 -> bf16 into wbf[2][256][4096] (lives in d_out
// scratch; consumed by proj before attn overwrites d_out).
// ---------------------------------------------------------------------------
__global__ __launch_bounds__(256) void conv_w_kernel(
    const float* __restrict__ EW, const float* __restrict__ FW,
    short* __restrict__ wbf) {
  const int idx = blockIdx.x * 256 + threadIdx.x;  // 0..524287 (f32x4 units)
  const int half = 262144;                         // 1M f32 per matrix / 4
  f32x4 v = (idx < half) ? *(const f32x4*)(EW + (size_t)idx * 4)
                         : *(const f32x4*)(FW + (size_t)(idx - half) * 4);
  u32x2 h = {cvtpk(v[0], v[1]), cvtpk(v[2], v[3])};
  *(u32x2*)(wbf + (size_t)idx * 4) = h;
}

// ---------------------------------------------------------------------------
// Stage 1: full projection, one block per (b,p). grid 64 (XCD-chunked),
// 512 thr = 8 waves (4m x 2n of 64x64). K=4096 in 64 steps of BK=64,
// double-buffered. W staged via global_load_lds from pre-converted bf16
// (pre-swizzled source); X reg-transposed + cvt_pk. Outputs directly:
//   p=0: kp[b][k][d] bf16 (+Eb)      p=1: vpt[b][d][k] bf16 (+Fb)
// p=1 computes the transposed GEMM by swapping MFMA operands.
// ---------------------------------------------------------------------------
__global__ __launch_bounds__(512) void proj_kernel(
    const float* __restrict__ Kin, const float* __restrict__ Vin,
    const short* __restrict__ wbf, const float* __restrict__ Eb,
    const float* __restrict__ Fb, short* __restrict__ kp,
    short* __restrict__ vpt) {
  const int bid = blockIdx.x;                // 0..63
  const int wk = (bid & 7) * 8 + (bid >> 3); // XCD x owns wk [8x, 8x+8)
  const int p = wk >> 5;                     // XCDs 0-3: p=0, 4-7: p=1
  const int b = wk & 31;

  const float* __restrict__ X = (p == 0 ? Kin : Vin) + (size_t)b * (N_SEQ * D_HEAD);
  const short* __restrict__ wp = wbf + (size_t)p * (KP_DIM * N_SEQ);

  __shared__ __align__(16) short lw[2][KP_DIM * 64];  // 32KB x2: W tile [256 k][64 n]
  __shared__ __align__(16) short xt[2][D_HEAD * 64];  // 16KB x2: X^T tile [128 d][64 n]

  const int t = threadIdx.x;
  const int lane = t & 63;
  const int w = t >> 6;            // 0..7
  const int wm = (w >> 1) * 64;    // k offset of wave
  const int wn = (w & 1) * 64;     // d offset of wave
  const int l15 = lane & 15;
  const int l4 = lane >> 4;
  const int dq = t & 31;           // d-quad for X staging
  const int ng = t >> 5;           // n-group (0..15) for X staging

  f32x4 acc[4][4];
#pragma unroll
  for (int i = 0; i < 4; ++i)
#pragma unroll
    for (int j = 0; j < 4; ++j) acc[i][j] = (f32x4){0.f, 0.f, 0.f, 0.f};

  f32x4 xreg[4];

  // ---- prologue: stage iter 0 ----
#pragma unroll
  for (int i = 0; i < 4; ++i) {
    int g = t + i * 512;           // 16B chunk id 0..2047
    int row = g >> 3, c = g & 7;
    __builtin_amdgcn_global_load_lds(
        (const __attribute__((address_space(1))) void*)(wp + (size_t)row * N_SEQ +
                                                        ((c ^ swz8(row)) << 3)),
        (__attribute__((address_space(3))) void*)(&lw[0][g * 8]), 16, 0, 0);
  }
#pragma unroll
  for (int i = 0; i < 4; ++i)
    xreg[i] = *(const f32x4*)(X + (size_t)(ng * 4 + i) * D_HEAD + dq * 4);
  asm volatile("s_waitcnt vmcnt(0)" ::: "memory");
#pragma unroll
  for (int j = 0; j < 4; ++j) {
    int drow = dq * 4 + j;
    u32x2 hv = {cvtpk(xreg[0][j], xreg[1][j]), cvtpk(xreg[2][j], xreg[3][j])};
    *(u32x2*)(&xt[0][drow * 64 + ((ng * 4) ^ (swz8(drow) << 3))]) = hv;
  }
  __syncthreads();

  // ---- main loop ----
#pragma unroll 2
  for (int it = 0; it < 64; ++it) {
    const int cur = it & 1, nxt = cur ^ 1;
    if (it < 63) {
      const int nc = (it + 1) * 64;
#pragma unroll
      for (int i = 0; i < 4; ++i) {
        int g = t + i * 512;
        int row = g >> 3, c = g & 7;
        __builtin_amdgcn_global_load_lds(
            (const __attribute__((address_space(1))) void*)(wp + (size_t)row * N_SEQ + nc +
                                                            ((c ^ swz8(row)) << 3)),
            (__attribute__((address_space(3))) void*)(&lw[nxt][g * 8]), 16, 0, 0);
      }
#pragma unroll
      for (int i = 0; i < 4; ++i)
        xreg[i] = *(const f32x4*)(X + (size_t)(nc + ng * 4 + i) * D_HEAD + dq * 4);
    }
    // ---- compute on buf[cur] ----
    if (p == 0) {
#pragma unroll
      for (int ks2 = 0; ks2 < 2; ++ks2) {
        const int col0 = ks2 * 32 + l4 * 8;
        bf16x8 a[4], bb[4];
#pragma unroll
        for (int mt = 0; mt < 4; ++mt) {
          int row = wm + mt * 16 + l15;
          a[mt] = *(const bf16x8*)(&lw[cur][row * 64 + (col0 ^ (swz8(row) << 3))]);
        }
#pragma unroll
        for (int nt = 0; nt < 4; ++nt) {
          int row = wn + nt * 16 + l15;
          bb[nt] = *(const bf16x8*)(&xt[cur][row * 64 + (col0 ^ (swz8(row) << 3))]);
        }
#pragma unroll
        for (int mt = 0; mt < 4; ++mt)
#pragma unroll
          for (int nt = 0; nt < 4; ++nt)
            acc[mt][nt] = __builtin_amdgcn_mfma_f32_16x16x32_bf16(a[mt], bb[nt], acc[mt][nt], 0, 0, 0);
      }
    } else {
#pragma unroll
      for (int ks2 = 0; ks2 < 2; ++ks2) {
        const int col0 = ks2 * 32 + l4 * 8;
        bf16x8 a[4], bb[4];
#pragma unroll
        for (int mt = 0; mt < 4; ++mt) {
          int row = wm + mt * 16 + l15;
          a[mt] = *(const bf16x8*)(&lw[cur][row * 64 + (col0 ^ (swz8(row) << 3))]);
        }
#pragma unroll
        for (int nt = 0; nt < 4; ++nt) {
          int row = wn + nt * 16 + l15;
          bb[nt] = *(const bf16x8*)(&xt[cur][row * 64 + (col0 ^ (swz8(row) << 3))]);
        }
#pragma unroll
        for (int mt = 0; mt < 4; ++mt)
#pragma unroll
          for (int nt = 0; nt < 4; ++nt)
            acc[mt][nt] = __builtin_amdgcn_mfma_f32_16x16x32_bf16(bb[nt], a[mt], acc[mt][nt], 0, 0, 0);
      }
    }
    if (it < 63) {
      asm volatile("s_waitcnt vmcnt(0)" ::: "memory");
#pragma unroll
      for (int j = 0; j < 4; ++j) {
        int drow = dq * 4 + j;
        u32x2 hv = {cvtpk(xreg[0][j], xreg[1][j]), cvtpk(xreg[2][j], xreg[3][j])};
        *(u32x2*)(&xt[nxt][drow * 64 + ((ng * 4) ^ (swz8(drow) << 3))]) = hv;
      }
    }
    __syncthreads();
  }

  // ---- epilogue: bias + bf16 + store ----
  if (p == 0) {
    short* __restrict__ outp = kp + (size_t)b * (KP_DIM * D_HEAD);
#pragma unroll
    for (int mt = 0; mt < 4; ++mt) {
      f32x4 bv = *(const f32x4*)(Eb + wm + mt * 16 + l4 * 4);
#pragma unroll
      for (int nt = 0; nt < 4; ++nt)
#pragma unroll
        for (int r = 0; r < 4; ++r) {
          int k = wm + mt * 16 + l4 * 4 + r;
          int d = wn + nt * 16 + l15;
          outp[(size_t)k * D_HEAD + d] = f2bf(acc[mt][nt][r] + bv[r]);
        }
    }
  } else {
    short* __restrict__ outp = vpt + (size_t)b * (KP_DIM * D_HEAD);
#pragma unroll
    for (int mt = 0; mt < 4; ++mt) {
      float fb = Fb[wm + mt * 16 + l15];
#pragma unroll
      for (int nt = 0; nt < 4; ++nt)
#pragma unroll
        for (int r = 0; r < 4; ++r) {
          int d = wn + nt * 16 + l4 * 4 + r;  // acc rows = d (swapped operands)
          int k = wm + mt * 16 + l15;
          outp[(size_t)d * KP_DIM + k] = f2bf(acc[mt][nt][r] + fb);
        }
    }
  }
}

// ---------------------------------------------------------------------------
// Stage 2: attention (unchanged from R3). grid 2048 (XCD-swizzled), 256 thr.
// ---------------------------------------------------------------------------
static __device__ __forceinline__ void stage_tile_swz(
    short* lds, const char* src, int rowStrideBytes, int w, int lane) {
#pragma unroll
  for (int i = 0; i < 8; ++i) {
    int cb = w * 8 + i;
    int g = cb * 64 + lane;
    int row = g >> 4;
    int c = g & 15;
    const char* gp = src + (size_t)row * rowStrideBytes + ((c ^ (row & 7)) << 4);
    __builtin_amdgcn_global_load_lds(
        (const __attribute__((address_space(1))) void*)gp,
        (__attribute__((address_space(3))) void*)(lds + (size_t)cb * 512),
        16, 0, 0);
  }
}

static __device__ __forceinline__ bf16x8 read_frag(const short* lds, int row, int chunk) {
  return *(const bf16x8*)(&lds[row * 128 + ((chunk ^ (row & 7)) << 3)]);
}

__global__ __launch_bounds__(256) void attn_kernel(
    const float* __restrict__ Q, const short* __restrict__ kp,
    const short* __restrict__ vpt, float* __restrict__ out) {
  const int bid = blockIdx.x;
  const int wk = (bid & 7) * 256 + (bid >> 3);
  const int b = wk >> 6;
  const int tileI = wk & 63;
  const int n0 = tileI * 64;
  const int t = threadIdx.x;
  const int lane = t & 63;
  const int w = t >> 6;
  const int l15 = lane & 15, l4 = lane >> 4;

  __shared__ __align__(16) short lkv[128 * 128];
  __shared__ __align__(16) short lp[64 * 256];

  const short* __restrict__ kpb = kp + (size_t)b * (KP_DIM * D_HEAD);
  const short* __restrict__ vptb = vpt + (size_t)b * (KP_DIM * D_HEAD);

  stage_tile_swz(lkv, (const char*)kpb, 256, w, lane);

  bf16x8 qf[4];
  {
    const float* qrow = Q + ((size_t)b * N_SEQ + n0 + w * 16 + l15) * D_HEAD;
#pragma unroll
    for (int ks = 0; ks < 4; ++ks) {
      f32x4 q0 = *(const f32x4*)(qrow + ks * 32 + l4 * 8);
      f32x4 q1 = *(const f32x4*)(qrow + ks * 32 + l4 * 8 + 4);
      qf[ks] = (bf16x8){f2bf(q0[0]), f2bf(q0[1]), f2bf(q0[2]), f2bf(q0[3]),
                        f2bf(q1[0]), f2bf(q1[1]), f2bf(q1[2]), f2bf(q1[3])};
    }
  }
  asm volatile("s_waitcnt vmcnt(0)" ::: "memory");
  __syncthreads();

  f32x4 accs[16];
#pragma unroll
  for (int i = 0; i < 16; ++i) accs[i] = (f32x4){0.f, 0.f, 0.f, 0.f};

#pragma unroll
  for (int h = 0; h < 2; ++h) {
    if (h == 1) {
      __syncthreads();
      stage_tile_swz(lkv, (const char*)kpb + 128 * 256, 256, w, lane);
      asm volatile("s_waitcnt vmcnt(0)" ::: "memory");
      __syncthreads();
    }
#pragma unroll
    for (int ks = 0; ks < 4; ++ks) {
#pragma unroll
      for (int ntl = 0; ntl < 8; ++ntl) {
        bf16x8 bb = read_frag(lkv, ntl * 16 + l15, ks * 4 + l4);
        accs[h * 8 + ntl] =
            __builtin_amdgcn_mfma_f32_16x16x32_bf16(qf[ks], bb, accs[h * 8 + ntl], 0, 0, 0);
      }
    }
  }

  const float scale = 0.08838834764831845f;
#pragma unroll
  for (int r = 0; r < 4; ++r) {
    float m = -1e30f;
#pragma unroll
    for (int nt = 0; nt < 16; ++nt) {
      float v = accs[nt][r] * scale;
      accs[nt][r] = v;
      m = fmaxf(m, v);
    }
    m = fmaxf(m, __shfl_xor(m, 1));
    m = fmaxf(m, __shfl_xor(m, 2));
    m = fmaxf(m, __shfl_xor(m, 4));
    m = fmaxf(m, __shfl_xor(m, 8));
    float sum = 0.f;
#pragma unroll
    for (int nt = 0; nt < 16; ++nt) {
      float e = __expf(accs[nt][r] - m);
      accs[nt][r] = e;
      sum += e;
    }
    sum += __shfl_xor(sum, 1);
    sum += __shfl_xor(sum, 2);
    sum += __shfl_xor(sum, 4);
    sum += __shfl_xor(sum, 8);
    float inv = 1.0f / sum;
    int row = w * 16 + l4 * 4 + r;
#pragma unroll
    for (int nt = 0; nt < 16; ++nt) {
      int col = nt * 16 + l15;
      lp[row * 256 + (col ^ ((row & 7) << 3))] = f2bf(accs[nt][r] * inv);
    }
  }

  f32x4 acco[8];
#pragma unroll
  for (int i = 0; i < 8; ++i) acco[i] = (f32x4){0.f, 0.f, 0.f, 0.f};

#pragma unroll
  for (int h = 0; h < 2; ++h) {
    __syncthreads();
    stage_tile_swz(lkv, (const char*)vptb + h * 256, 512, w, lane);
    asm volatile("s_waitcnt vmcnt(0)" ::: "memory");
    __syncthreads();
#pragma unroll
    for (int ksl = 0; ksl < 4; ++ksl) {
      int kk = h * 128 + ksl * 32 + l4 * 8;
      int prow = w * 16 + l15;
      bf16x8 ap = *(const bf16x8*)(&lp[prow * 256 + (kk ^ ((prow & 7) << 3))]);
#pragma unroll
      for (int ntv = 0; ntv < 8; ++ntv) {
        bf16x8 bv = read_frag(lkv, ntv * 16 + l15, ksl * 4 + l4);
        acco[ntv] = __builtin_amdgcn_mfma_f32_16x16x32_bf16(ap, bv, acco[ntv], 0, 0, 0);
      }
    }
  }

  float* __restrict__ ob = out + ((size_t)b * N_SEQ + n0 + w * 16) * D_HEAD;
#pragma unroll
  for (int ntv = 0; ntv < 8; ++ntv)
#pragma unroll
    for (int r = 0; r < 4; ++r)
      ob[(size_t)(l4 * 4 + r) * D_HEAD + ntv * 16 + l15] = acco[ntv][r];
}

// ---------------------------------------------------------------------------
extern "C" void kernel_launch(void* const* d_in, const int* in_sizes, int n_in,
                              void* d_out, int out_size, void* d_ws, size_t ws_size,
                              hipStream_t stream) {
  const float* Q  = (const float*)d_in[0];
  const float* K  = (const float*)d_in[1];
  const float* V  = (const float*)d_in[2];
  const float* EW = (const float*)d_in[3];
  const float* Eb = (const float*)d_in[4];
  const float* FW = (const float*)d_in[5];
  const float* Fb = (const float*)d_in[6];
  float* out = (float*)d_out;

  short* wbf = (short*)d_out;  // 4MB W-bf16 scratch inside d_out (dead before attn)
  short* kpb = (short*)d_ws;
  short* vpt = (short*)((char*)d_ws + (size_t)32 * KP_DIM * D_HEAD * 2);

  conv_w_kernel<<<dim3(2048), dim3(256), 0, stream>>>(EW, FW, wbf);
  proj_kernel<<<dim3(64), dim3(512), 0, stream>>>(K, V, wbf, Eb, Fb, kpb, vpt);
  attn_kernel<<<dim3(2048), dim3(256), 0, stream>>>(Q, kpb, vpt, out);
}

// Round 5
// 123.320 us; speedup vs baseline: 1.2890x; 1.2890x over previous
//
#include <hip/hip_runtime.h>
#include <cstdint>
#include <cstddef>

#define N_SEQ 4096
#define D_HEAD 128
#define KP_DIM 256

typedef __attribute__((ext_vector_type(4))) float f32x4;
typedef __attribute__((ext_vector_type(8))) short bf16x8;
typedef __attribute__((ext_vector_type(4))) short s16x4;
typedef __attribute__((ext_vector_type(2))) unsigned int u32x2;

static __device__ __forceinline__ short f2bf(float f) {
  uint32_t u = __builtin_bit_cast(uint32_t, f);
  u += 0x7FFFu + ((u >> 16) & 1u);
  return (short)(u >> 16);
}

static __device__ __forceinline__ unsigned int cvtpk(float a, float b) {
  unsigned int r;
  asm("v_cvt_pk_bf16_f32 %0, %1, %2" : "=v"(r) : "v"(a), "v"(b));
  return r;
}

static __device__ __forceinline__ int swz8(int r) { return (r ^ (r >> 2)) & 7; }

// ---------------------------------------------------------------------------
// Stage 0: convert E_W,F_W f32 -> bf16 wbf[2][256][4096] (d_out scratch, low 4MB)
// ---------------------------------------------------------------------------
__global__ __launch_bounds__(256) void conv_w_kernel(
    const float* __restrict__ EW, const float* __restrict__ FW,
    short* __restrict__ wbf) {
  const int idx = blockIdx.x * 256 + threadIdx.x;
  const int half = 262144;
  f32x4 v = (idx < half) ? *(const f32x4*)(EW + (size_t)idx * 4)
                         : *(const f32x4*)(FW + (size_t)(idx - half) * 4);
  u32x2 h = {cvtpk(v[0], v[1]), cvtpk(v[2], v[3])};
  *(u32x2*)(wbf + (size_t)idx * 4) = h;
}

// ---------------------------------------------------------------------------
// Stage 1: partial projections. grid 256 (XCD-chunked: each XCD one (p,s),
// W slice L2-resident), 512 thr = 8 waves (4k x 2d of 64x64).
// pws[b][p][s][k 256][d 128] f32 = sum over n-chunk s. Double-buffered LDS;
// W staged via global_load_lds from bf16 wbf (pre-swizzled source);
// X reg-loaded f32, cvt_pk -> bf16, reg-transposed into LDS.
// Wait discipline: X issued first, W gload_lds second -> vmcnt(4) frees the
// X convert while W still flies; vmcnt(0) only just before the barrier.
// ---------------------------------------------------------------------------
__global__ __launch_bounds__(512) void proj_partial_kernel(
    const float* __restrict__ Kin, const float* __restrict__ Vin,
    const short* __restrict__ wbf, float* __restrict__ pws) {
  const int bid = blockIdx.x;                  // 0..255
  const int wk = (bid & 7) * 32 + (bid >> 3);  // XCD x owns wk [32x, 32x+32)
  const int b = wk & 31;
  const int s = (wk >> 5) & 3;
  const int p = wk >> 7;

  const float* __restrict__ X = (p == 0 ? Kin : Vin) + (size_t)b * (N_SEQ * D_HEAD);
  const short* __restrict__ wp = wbf + (size_t)p * (KP_DIM * N_SEQ);
  float* __restrict__ outp = pws + ((((size_t)b * 2 + p) * 4) + s) * (KP_DIM * D_HEAD);

  __shared__ __align__(16) short lw[2][KP_DIM * 64];  // 32KB x2
  __shared__ __align__(16) short xt[2][D_HEAD * 64];  // 16KB x2

  const int t = threadIdx.x;
  const int lane = t & 63;
  const int w = t >> 6;
  const int wm = (w >> 1) * 64;
  const int wn = (w & 1) * 64;
  const int l15 = lane & 15;
  const int l4 = lane >> 4;
  const int dq = t & 31;   // d-quad for X staging
  const int ng = t >> 5;   // n-group 0..15 for X staging

  const int n0 = s * 1024;

  f32x4 acc[4][4];
#pragma unroll
  for (int i = 0; i < 4; ++i)
#pragma unroll
    for (int j = 0; j < 4; ++j) acc[i][j] = (f32x4){0.f, 0.f, 0.f, 0.f};

  f32x4 xreg[4];

  // ---- prologue: stage iter 0 (X first, then W) ----
#pragma unroll
  for (int i = 0; i < 4; ++i)
    xreg[i] = *(const f32x4*)(X + (size_t)(n0 + ng * 4 + i) * D_HEAD + dq * 4);
#pragma unroll
  for (int i = 0; i < 4; ++i) {
    int g = t + i * 512;
    int row = g >> 3, c = g & 7;
    __builtin_amdgcn_global_load_lds(
        (const __attribute__((address_space(1))) void*)(wp + (size_t)row * N_SEQ + n0 +
                                                        ((c ^ swz8(row)) << 3)),
        (__attribute__((address_space(3))) void*)(&lw[0][g * 8]), 16, 0, 0);
  }
  asm volatile("s_waitcnt vmcnt(4)" ::: "memory");
#pragma unroll
  for (int j = 0; j < 4; ++j) {
    int drow = dq * 4 + j;
    u32x2 hv = {cvtpk(xreg[0][j], xreg[1][j]), cvtpk(xreg[2][j], xreg[3][j])};
    *(u32x2*)(&xt[0][drow * 64 + ((ng * 4) ^ (swz8(drow) << 3))]) = hv;
  }
  asm volatile("s_waitcnt vmcnt(0)" ::: "memory");
  __syncthreads();

  // ---- main loop: 16 iters of BK=64 ----
  for (int it = 0; it < 16; ++it) {
    const int cur = it & 1, nxt = cur ^ 1;
    if (it < 15) {
      const int nc = n0 + (it + 1) * 64;
#pragma unroll
      for (int i = 0; i < 4; ++i)
        xreg[i] = *(const f32x4*)(X + (size_t)(nc + ng * 4 + i) * D_HEAD + dq * 4);
#pragma unroll
      for (int i = 0; i < 4; ++i) {
        int g = t + i * 512;
        int row = g >> 3, c = g & 7;
        __builtin_amdgcn_global_load_lds(
            (const __attribute__((address_space(1))) void*)(wp + (size_t)row * N_SEQ + nc +
                                                            ((c ^ swz8(row)) << 3)),
            (__attribute__((address_space(3))) void*)(&lw[nxt][g * 8]), 16, 0, 0);
      }
    }
    // ---- compute on buf[cur] ----
#pragma unroll
    for (int ks2 = 0; ks2 < 2; ++ks2) {
      const int col0 = ks2 * 32 + l4 * 8;
      bf16x8 a[4], bb[4];
#pragma unroll
      for (int mt = 0; mt < 4; ++mt) {
        int row = wm + mt * 16 + l15;
        a[mt] = *(const bf16x8*)(&lw[cur][row * 64 + (col0 ^ (swz8(row) << 3))]);
      }
#pragma unroll
      for (int nt = 0; nt < 4; ++nt) {
        int row = wn + nt * 16 + l15;
        bb[nt] = *(const bf16x8*)(&xt[cur][row * 64 + (col0 ^ (swz8(row) << 3))]);
      }
#pragma unroll
      for (int mt = 0; mt < 4; ++mt)
#pragma unroll
        for (int nt = 0; nt < 4; ++nt)
          acc[mt][nt] = __builtin_amdgcn_mfma_f32_16x16x32_bf16(a[mt], bb[nt], acc[mt][nt], 0, 0, 0);
    }
    if (it < 15) {
      asm volatile("s_waitcnt vmcnt(4)" ::: "memory");  // X landed; W may still fly
#pragma unroll
      for (int j = 0; j < 4; ++j) {
        int drow = dq * 4 + j;
        u32x2 hv = {cvtpk(xreg[0][j], xreg[1][j]), cvtpk(xreg[2][j], xreg[3][j])};
        *(u32x2*)(&xt[nxt][drow * 64 + ((ng * 4) ^ (swz8(drow) << 3))]) = hv;
      }
      asm volatile("s_waitcnt vmcnt(0)" ::: "memory");  // W[nxt] in LDS
    }
    __syncthreads();
  }

  // ---- write f32 partials ----
#pragma unroll
  for (int mt = 0; mt < 4; ++mt)
#pragma unroll
    for (int nt = 0; nt < 4; ++nt)
#pragma unroll
      for (int r = 0; r < 4; ++r) {
        int kk = wm + mt * 16 + l4 * 4 + r;
        int dd = wn + nt * 16 + l15;
        outp[kk * D_HEAD + dd] = acc[mt][nt][r];
      }
}

// ---------------------------------------------------------------------------
// Stage 1b: reduce 4 partials + bias -> kp[b][k][d] bf16, vpt[b][d][k] bf16
// ---------------------------------------------------------------------------
__global__ __launch_bounds__(256) void reduce_bias_kernel(
    const float* __restrict__ pws, const float* __restrict__ Eb,
    const float* __restrict__ Fb, short* __restrict__ kp, short* __restrict__ vpt) {
  const int p = blockIdx.x & 1;
  const int b = blockIdx.x >> 1;
  const float* __restrict__ base = pws + (((size_t)b * 2 + p) * 4) * (KP_DIM * D_HEAD);
  const float* __restrict__ bias = (p == 0) ? Eb : Fb;
  const int t = threadIdx.x;
  __shared__ short tile[KP_DIM * D_HEAD];
  if (p == 0) {
    for (int i = t; i < KP_DIM * D_HEAD; i += 256) {
      int k = i >> 7;
      float v = base[i] + base[i + 32768] + base[i + 65536] + base[i + 98304] + bias[k];
      kp[(size_t)b * (KP_DIM * D_HEAD) + i] = f2bf(v);
    }
  } else {
    for (int i = t; i < KP_DIM * D_HEAD; i += 256) {
      int k = i >> 7, d = i & 127;
      float v = base[i] + base[i + 32768] + base[i + 65536] + base[i + 98304] + bias[k];
      tile[k * D_HEAD + (d ^ ((k & 15) << 3))] = f2bf(v);
    }
    __syncthreads();
    for (int i = t; i < KP_DIM * D_HEAD; i += 256) {
      int d = i >> 8, k = i & 255;
      vpt[(size_t)b * (KP_DIM * D_HEAD) + i] = tile[k * D_HEAD + (d ^ ((k & 15) << 3))];
    }
  }
}

// ---------------------------------------------------------------------------
// Stage 2: attention (unchanged). grid 2048 (XCD-swizzled), 256 thr.
// ---------------------------------------------------------------------------
static __device__ __forceinline__ void stage_tile_swz(
    short* lds, const char* src, int rowStrideBytes, int w, int lane) {
#pragma unroll
  for (int i = 0; i < 8; ++i) {
    int cb = w * 8 + i;
    int g = cb * 64 + lane;
    int row = g >> 4;
    int c = g & 15;
    const char* gp = src + (size_t)row * rowStrideBytes + ((c ^ (row & 7)) << 4);
    __builtin_amdgcn_global_load_lds(
        (const __attribute__((address_space(1))) void*)gp,
        (__attribute__((address_space(3))) void*)(lds + (size_t)cb * 512),
        16, 0, 0);
  }
}

static __device__ __forceinline__ bf16x8 read_frag(const short* lds, int row, int chunk) {
  return *(const bf16x8*)(&lds[row * 128 + ((chunk ^ (row & 7)) << 3)]);
}

__global__ __launch_bounds__(256) void attn_kernel(
    const float* __restrict__ Q, const short* __restrict__ kp,
    const short* __restrict__ vpt, float* __restrict__ out) {
  const int bid = blockIdx.x;
  const int wk = (bid & 7) * 256 + (bid >> 3);
  const int b = wk >> 6;
  const int tileI = wk & 63;
  const int n0 = tileI * 64;
  const int t = threadIdx.x;
  const int lane = t & 63;
  const int w = t >> 6;
  const int l15 = lane & 15, l4 = lane >> 4;

  __shared__ __align__(16) short lkv[128 * 128];
  __shared__ __align__(16) short lp[64 * 256];

  const short* __restrict__ kpb = kp + (size_t)b * (KP_DIM * D_HEAD);
  const short* __restrict__ vptb = vpt + (size_t)b * (KP_DIM * D_HEAD);

  stage_tile_swz(lkv, (const char*)kpb, 256, w, lane);

  bf16x8 qf[4];
  {
    const float* qrow = Q + ((size_t)b * N_SEQ + n0 + w * 16 + l15) * D_HEAD;
#pragma unroll
    for (int ks = 0; ks < 4; ++ks) {
      f32x4 q0 = *(const f32x4*)(qrow + ks * 32 + l4 * 8);
      f32x4 q1 = *(const f32x4*)(qrow + ks * 32 + l4 * 8 + 4);
      qf[ks] = (bf16x8){f2bf(q0[0]), f2bf(q0[1]), f2bf(q0[2]), f2bf(q0[3]),
                        f2bf(q1[0]), f2bf(q1[1]), f2bf(q1[2]), f2bf(q1[3])};
    }
  }
  asm volatile("s_waitcnt vmcnt(0)" ::: "memory");
  __syncthreads();

  f32x4 accs[16];
#pragma unroll
  for (int i = 0; i < 16; ++i) accs[i] = (f32x4){0.f, 0.f, 0.f, 0.f};

#pragma unroll
  for (int h = 0; h < 2; ++h) {
    if (h == 1) {
      __syncthreads();
      stage_tile_swz(lkv, (const char*)kpb + 128 * 256, 256, w, lane);
      asm volatile("s_waitcnt vmcnt(0)" ::: "memory");
      __syncthreads();
    }
#pragma unroll
    for (int ks = 0; ks < 4; ++ks) {
#pragma unroll
      for (int ntl = 0; ntl < 8; ++ntl) {
        bf16x8 bb = read_frag(lkv, ntl * 16 + l15, ks * 4 + l4);
        accs[h * 8 + ntl] =
            __builtin_amdgcn_mfma_f32_16x16x32_bf16(qf[ks], bb, accs[h * 8 + ntl], 0, 0, 0);
      }
    }
  }

  const float scale = 0.08838834764831845f;
#pragma unroll
  for (int r = 0; r < 4; ++r) {
    float m = -1e30f;
#pragma unroll
    for (int nt = 0; nt < 16; ++nt) {
      float v = accs[nt][r] * scale;
      accs[nt][r] = v;
      m = fmaxf(m, v);
    }
    m = fmaxf(m, __shfl_xor(m, 1));
    m = fmaxf(m, __shfl_xor(m, 2));
    m = fmaxf(m, __shfl_xor(m, 4));
    m = fmaxf(m, __shfl_xor(m, 8));
    float sum = 0.f;
#pragma unroll
    for (int nt = 0; nt < 16; ++nt) {
      float e = __expf(accs[nt][r] - m);
      accs[nt][r] = e;
      sum += e;
    }
    sum += __shfl_xor(sum, 1);
    sum += __shfl_xor(sum, 2);
    sum += __shfl_xor(sum, 4);
    sum += __shfl_xor(sum, 8);
    float inv = 1.0f / sum;
    int row = w * 16 + l4 * 4 + r;
#pragma unroll
    for (int nt = 0; nt < 16; ++nt) {
      int col = nt * 16 + l15;
      lp[row * 256 + (col ^ ((row & 7) << 3))] = f2bf(accs[nt][r] * inv);
    }
  }

  f32x4 acco[8];
#pragma unroll
  for (int i = 0; i < 8; ++i) acco[i] = (f32x4){0.f, 0.f, 0.f, 0.f};

#pragma unroll
  for (int h = 0; h < 2; ++h) {
    __syncthreads();
    stage_tile_swz(lkv, (const char*)vptb + h * 256, 512, w, lane);
    asm volatile("s_waitcnt vmcnt(0)" ::: "memory");
    __syncthreads();
#pragma unroll
    for (int ksl = 0; ksl < 4; ++ksl) {
      int kk = h * 128 + ksl * 32 + l4 * 8;
      int prow = w * 16 + l15;
      bf16x8 ap = *(const bf16x8*)(&lp[prow * 256 + (kk ^ ((prow & 7) << 3))]);
#pragma unroll
      for (int ntv = 0; ntv < 8; ++ntv) {
        bf16x8 bv = read_frag(lkv, ntv * 16 + l15, ksl * 4 + l4);
        acco[ntv] = __builtin_amdgcn_mfma_f32_16x16x32_bf16(ap, bv, acco[ntv], 0, 0, 0);
      }
    }
  }

  float* __restrict__ ob = out + ((size_t)b * N_SEQ + n0 + w * 16) * D_HEAD;
#pragma unroll
  for (int ntv = 0; ntv < 8; ++ntv)
#pragma unroll
    for (int r = 0; r < 4; ++r)
      ob[(size_t)(l4 * 4 + r) * D_HEAD + ntv * 16 + l15] = acco[ntv][r];
}

// ---------------------------------------------------------------------------
extern "C" void kernel_launch(void* const* d_in, const int* in_sizes, int n_in,
                              void* d_out, int out_size, void* d_ws, size_t ws_size,
                              hipStream_t stream) {
  const float* Q  = (const float*)d_in[0];
  const float* K  = (const float*)d_in[1];
  const float* V  = (const float*)d_in[2];
  const float* EW = (const float*)d_in[3];
  const float* Eb = (const float*)d_in[4];
  const float* FW = (const float*)d_in[5];
  const float* Fb = (const float*)d_in[6];
  float* out = (float*)d_out;

  // d_out scratch layout (all dead before attn writes):
  //   [0, 4MB)  : wbf bf16 W
  //   [8MB, 41.5MB) : pws f32 partials
  short* wbf = (short*)d_out;
  float* pws = (float*)d_out + 2097152;  // +8MB
  short* kpb = (short*)d_ws;
  short* vpt = (short*)((char*)d_ws + (size_t)32 * KP_DIM * D_HEAD * 2);

  conv_w_kernel<<<dim3(2048), dim3(256), 0, stream>>>(EW, FW, wbf);
  proj_partial_kernel<<<dim3(256), dim3(512), 0, stream>>>(K, V, wbf, pws);
  reduce_bias_kernel<<<dim3(64), dim3(256), 0, stream>>>(pws, Eb, Fb, kpb, vpt);
  attn_kernel<<<dim3(2048), dim3(256), 0, stream>>>(Q, kpb, vpt, out);
}

// Round 6
// 103.488 us; speedup vs baseline: 1.5361x; 1.1916x over previous
//
#include <hip/hip_runtime.h>
#include <cstdint>
#include <cstddef>

#define N_SEQ 4096
#define D_HEAD 128
#define KP_DIM 256

typedef __attribute__((ext_vector_type(4))) float f32x4;
typedef __attribute__((ext_vector_type(8))) short bf16x8;
typedef __attribute__((ext_vector_type(4))) short s16x4;
typedef __attribute__((ext_vector_type(2))) unsigned int u32x2;

static __device__ __forceinline__ short f2bf(float f) {
  uint32_t u = __builtin_bit_cast(uint32_t, f);
  u += 0x7FFFu + ((u >> 16) & 1u);
  return (short)(u >> 16);
}

static __device__ __forceinline__ unsigned int cvtpk(float a, float b) {
  unsigned int r;
  asm("v_cvt_pk_bf16_f32 %0, %1, %2" : "=v"(r) : "v"(a), "v"(b));
  return r;
}

static __device__ __forceinline__ int swz8(int r) { return (r ^ (r >> 2)) & 7; }

// ---------------------------------------------------------------------------
// Stage 0: convert E_W,F_W f32 -> bf16 wbf[2][256][4096] (d_out scratch)
// ---------------------------------------------------------------------------
__global__ __launch_bounds__(256) void conv_w_kernel(
    const float* __restrict__ EW, const float* __restrict__ FW,
    short* __restrict__ wbf) {
  const int idx = blockIdx.x * 256 + threadIdx.x;
  const int half = 262144;
  f32x4 v = (idx < half) ? *(const f32x4*)(EW + (size_t)idx * 4)
                         : *(const f32x4*)(FW + (size_t)(idx - half) * 4);
  u32x2 h = {cvtpk(v[0], v[1]), cvtpk(v[2], v[3])};
  *(u32x2*)(wbf + (size_t)idx * 4) = h;
}

// ---------------------------------------------------------------------------
// Stage 1: partial projections (unchanged from R5). grid 256, 512 thr.
// ---------------------------------------------------------------------------
__global__ __launch_bounds__(512) void proj_partial_kernel(
    const float* __restrict__ Kin, const float* __restrict__ Vin,
    const short* __restrict__ wbf, float* __restrict__ pws) {
  const int bid = blockIdx.x;
  const int wk = (bid & 7) * 32 + (bid >> 3);
  const int b = wk & 31;
  const int s = (wk >> 5) & 3;
  const int p = wk >> 7;

  const float* __restrict__ X = (p == 0 ? Kin : Vin) + (size_t)b * (N_SEQ * D_HEAD);
  const short* __restrict__ wp = wbf + (size_t)p * (KP_DIM * N_SEQ);
  float* __restrict__ outp = pws + ((((size_t)b * 2 + p) * 4) + s) * (KP_DIM * D_HEAD);

  __shared__ __align__(16) short lw[2][KP_DIM * 64];
  __shared__ __align__(16) short xt[2][D_HEAD * 64];

  const int t = threadIdx.x;
  const int lane = t & 63;
  const int w = t >> 6;
  const int wm = (w >> 1) * 64;
  const int wn = (w & 1) * 64;
  const int l15 = lane & 15;
  const int l4 = lane >> 4;
  const int dq = t & 31;
  const int ng = t >> 5;

  const int n0 = s * 1024;

  f32x4 acc[4][4];
#pragma unroll
  for (int i = 0; i < 4; ++i)
#pragma unroll
    for (int j = 0; j < 4; ++j) acc[i][j] = (f32x4){0.f, 0.f, 0.f, 0.f};

  f32x4 xreg[4];

#pragma unroll
  for (int i = 0; i < 4; ++i)
    xreg[i] = *(const f32x4*)(X + (size_t)(n0 + ng * 4 + i) * D_HEAD + dq * 4);
#pragma unroll
  for (int i = 0; i < 4; ++i) {
    int g = t + i * 512;
    int row = g >> 3, c = g & 7;
    __builtin_amdgcn_global_load_lds(
        (const __attribute__((address_space(1))) void*)(wp + (size_t)row * N_SEQ + n0 +
                                                        ((c ^ swz8(row)) << 3)),
        (__attribute__((address_space(3))) void*)(&lw[0][g * 8]), 16, 0, 0);
  }
  asm volatile("s_waitcnt vmcnt(4)" ::: "memory");
#pragma unroll
  for (int j = 0; j < 4; ++j) {
    int drow = dq * 4 + j;
    u32x2 hv = {cvtpk(xreg[0][j], xreg[1][j]), cvtpk(xreg[2][j], xreg[3][j])};
    *(u32x2*)(&xt[0][drow * 64 + ((ng * 4) ^ (swz8(drow) << 3))]) = hv;
  }
  asm volatile("s_waitcnt vmcnt(0)" ::: "memory");
  __syncthreads();

  for (int it = 0; it < 16; ++it) {
    const int cur = it & 1, nxt = cur ^ 1;
    if (it < 15) {
      const int nc = n0 + (it + 1) * 64;
#pragma unroll
      for (int i = 0; i < 4; ++i)
        xreg[i] = *(const f32x4*)(X + (size_t)(nc + ng * 4 + i) * D_HEAD + dq * 4);
#pragma unroll
      for (int i = 0; i < 4; ++i) {
        int g = t + i * 512;
        int row = g >> 3, c = g & 7;
        __builtin_amdgcn_global_load_lds(
            (const __attribute__((address_space(1))) void*)(wp + (size_t)row * N_SEQ + nc +
                                                            ((c ^ swz8(row)) << 3)),
            (__attribute__((address_space(3))) void*)(&lw[nxt][g * 8]), 16, 0, 0);
      }
    }
#pragma unroll
    for (int ks2 = 0; ks2 < 2; ++ks2) {
      const int col0 = ks2 * 32 + l4 * 8;
      bf16x8 a[4], bb[4];
#pragma unroll
      for (int mt = 0; mt < 4; ++mt) {
        int row = wm + mt * 16 + l15;
        a[mt] = *(const bf16x8*)(&lw[cur][row * 64 + (col0 ^ (swz8(row) << 3))]);
      }
#pragma unroll
      for (int nt = 0; nt < 4; ++nt) {
        int row = wn + nt * 16 + l15;
        bb[nt] = *(const bf16x8*)(&xt[cur][row * 64 + (col0 ^ (swz8(row) << 3))]);
      }
#pragma unroll
      for (int mt = 0; mt < 4; ++mt)
#pragma unroll
        for (int nt = 0; nt < 4; ++nt)
          acc[mt][nt] = __builtin_amdgcn_mfma_f32_16x16x32_bf16(a[mt], bb[nt], acc[mt][nt], 0, 0, 0);
    }
    if (it < 15) {
      asm volatile("s_waitcnt vmcnt(4)" ::: "memory");
#pragma unroll
      for (int j = 0; j < 4; ++j) {
        int drow = dq * 4 + j;
        u32x2 hv = {cvtpk(xreg[0][j], xreg[1][j]), cvtpk(xreg[2][j], xreg[3][j])};
        *(u32x2*)(&xt[nxt][drow * 64 + ((ng * 4) ^ (swz8(drow) << 3))]) = hv;
      }
      asm volatile("s_waitcnt vmcnt(0)" ::: "memory");
    }
    __syncthreads();
  }

#pragma unroll
  for (int mt = 0; mt < 4; ++mt)
#pragma unroll
    for (int nt = 0; nt < 4; ++nt)
#pragma unroll
      for (int r = 0; r < 4; ++r) {
        int kk = wm + mt * 16 + l4 * 4 + r;
        int dd = wn + nt * 16 + l15;
        outp[kk * D_HEAD + dd] = acc[mt][nt][r];
      }
}

// ---------------------------------------------------------------------------
// Stage 1b: reduce 4 partials + bias. grid 128 (4 blocks per b: 2x kp halves,
// 2x vpt k-halves with 32KB transpose tile).
// ---------------------------------------------------------------------------
__global__ __launch_bounds__(256) void reduce_bias_kernel(
    const float* __restrict__ pws, const float* __restrict__ Eb,
    const float* __restrict__ Fb, short* __restrict__ kp, short* __restrict__ vpt) {
  const int sub = blockIdx.x & 3;
  const int b = blockIdx.x >> 2;
  const int t = threadIdx.x;
  __shared__ short tile[128 * 128];
  if (sub < 2) {
    const float* __restrict__ base = pws + ((size_t)b * 2) * 4 * 32768;
    const int off = sub * 16384;
    for (int i = t; i < 16384; i += 256) {
      int ii = off + i;
      int k = ii >> 7;
      float v = base[ii] + base[ii + 32768] + base[ii + 65536] + base[ii + 98304] + Eb[k];
      kp[(size_t)b * 32768 + ii] = f2bf(v);
    }
  } else {
    const int kh = sub - 2;
    const float* __restrict__ base = pws + (((size_t)b * 2 + 1) * 4) * 32768 + kh * 16384;
    for (int i = t; i < 16384; i += 256) {
      int kl = i >> 7, d = i & 127;
      float v = base[i] + base[i + 32768] + base[i + 65536] + base[i + 98304] + Fb[kh * 128 + kl];
      tile[kl * 128 + (d ^ ((kl & 15) << 3))] = f2bf(v);
    }
    __syncthreads();
    for (int i = t; i < 16384; i += 256) {
      int d = i >> 7, kl = i & 127;
      vpt[(size_t)b * 32768 + d * 256 + kh * 128 + kl] = tile[kl * 128 + (d ^ ((kl & 15) << 3))];
    }
  }
}

// ---------------------------------------------------------------------------
// Stage 2: persistent attention. grid 256 (1 block/CU), 512 thr = 8 waves.
// Block (b, slice of 512 rows). kp+vpt staged to LDS ONCE; then 4 tile-rounds
// of 128 rows (16/wave) with ZERO barriers: swapped-operand QK^T (lane owns
// row n), 2-shuffle softmax, P transposed through wave-private 2KB LDS.
// ---------------------------------------------------------------------------
__global__ __launch_bounds__(512, 2) void attn_kernel(
    const float* __restrict__ Q, const short* __restrict__ kp,
    const short* __restrict__ vpt, float* __restrict__ out) {
  const int b = blockIdx.x >> 3;
  const int slice = blockIdx.x & 7;
  const int t = threadIdx.x;
  const int lane = t & 63;
  const int w = t >> 6;
  const int l15 = lane & 15, l4 = lane >> 4;

  __shared__ __align__(16) short lkp[256 * 128];   // 64KB  kp[k][d]
  __shared__ __align__(16) short lvpt[128 * 256];  // 64KB  vpt[d][k]
  __shared__ __align__(16) short lp[8][1024];      // 16KB  wave-private P quarter

  const short* __restrict__ kpb = kp + (size_t)b * 32768;
  const short* __restrict__ vptb = vpt + (size_t)b * 32768;

  // ---- stage kp + vpt once (swizzled source, linear LDS dest) ----
#pragma unroll
  for (int i = 0; i < 8; ++i) {
    int g = (w * 8 + i) * 64 + lane;
    int row = g >> 4, c = g & 15;
    __builtin_amdgcn_global_load_lds(
        (const __attribute__((address_space(1))) void*)(kpb + (size_t)row * 128 +
                                                        ((c ^ (row & 7)) << 3)),
        (__attribute__((address_space(3))) void*)(&lkp[g * 8]), 16, 0, 0);
  }
#pragma unroll
  for (int i = 0; i < 8; ++i) {
    int g = (w * 8 + i) * 64 + lane;
    int row = g >> 5, c = g & 31;
    __builtin_amdgcn_global_load_lds(
        (const __attribute__((address_space(1))) void*)(vptb + (size_t)row * 256 +
                                                        ((c ^ (row & 7)) << 3)),
        (__attribute__((address_space(3))) void*)(&lvpt[g * 8]), 16, 0, 0);
  }
  asm volatile("s_waitcnt vmcnt(0)" ::: "memory");
  __syncthreads();

  short* lpw = &lp[w][0];
  const float scale = 0.08838834764831845f;  // 1/sqrt(128)
  f32x4 qA[8], qB[8];

#define QLOAD(DST, TILE_I)                                                          \
  do {                                                                              \
    const float* qr_ = Q + ((size_t)b * N_SEQ + slice * 512 + (TILE_I) * 128 +      \
                            w * 16 + l15) * D_HEAD;                                 \
    _Pragma("unroll") for (int ks_ = 0; ks_ < 4; ++ks_) {                           \
      DST[2 * ks_] = *(const f32x4*)(qr_ + ks_ * 32 + l4 * 8);                      \
      DST[2 * ks_ + 1] = *(const f32x4*)(qr_ + ks_ * 32 + l4 * 8 + 4);              \
    }                                                                               \
  } while (0)

#define TILE_BODY(QC, QN, TILE_I, PREF)                                             \
  do {                                                                              \
    bf16x8 qf[4];                                                                   \
    _Pragma("unroll") for (int ks = 0; ks < 4; ++ks) {                              \
      union { unsigned int u[4]; bf16x8 v; } cv_;                                   \
      cv_.u[0] = cvtpk(QC[2 * ks][0], QC[2 * ks][1]);                               \
      cv_.u[1] = cvtpk(QC[2 * ks][2], QC[2 * ks][3]);                               \
      cv_.u[2] = cvtpk(QC[2 * ks + 1][0], QC[2 * ks + 1][1]);                       \
      cv_.u[3] = cvtpk(QC[2 * ks + 1][2], QC[2 * ks + 1][3]);                       \
      qf[ks] = cv_.v;                                                               \
    }                                                                               \
    if (PREF) QLOAD(QN, (TILE_I) + 1);                                              \
    f32x4 accs[16];                                                                 \
    _Pragma("unroll") for (int i = 0; i < 16; ++i)                                  \
        accs[i] = (f32x4){0.f, 0.f, 0.f, 0.f};                                      \
    _Pragma("unroll") for (int ks = 0; ks < 4; ++ks) {                              \
      _Pragma("unroll") for (int nt = 0; nt < 16; ++nt) {                           \
        bf16x8 af = *(const bf16x8*)(&lkp[(nt * 16 + l15) * 128 +                   \
                                          (((ks * 4 + l4) ^ (l15 & 7)) << 3)]);     \
        accs[nt] = __builtin_amdgcn_mfma_f32_16x16x32_bf16(af, qf[ks], accs[nt],    \
                                                           0, 0, 0);                \
      }                                                                             \
    }                                                                               \
    float m_ = -1e30f;                                                              \
    _Pragma("unroll") for (int nt = 0; nt < 16; ++nt)                               \
        _Pragma("unroll") for (int r = 0; r < 4; ++r) {                             \
      float v_ = accs[nt][r] * scale;                                               \
      accs[nt][r] = v_;                                                             \
      m_ = fmaxf(m_, v_);                                                           \
    }                                                                               \
    m_ = fmaxf(m_, __shfl_xor(m_, 16));                                             \
    m_ = fmaxf(m_, __shfl_xor(m_, 32));                                             \
    float s_ = 0.f;                                                                 \
    _Pragma("unroll") for (int nt = 0; nt < 16; ++nt)                               \
        _Pragma("unroll") for (int r = 0; r < 4; ++r) {                             \
      float e_ = __expf(accs[nt][r] - m_);                                          \
      accs[nt][r] = e_;                                                             \
      s_ += e_;                                                                     \
    }                                                                               \
    s_ += __shfl_xor(s_, 16);                                                       \
    s_ += __shfl_xor(s_, 32);                                                       \
    float inv_ = 1.0f / s_;                                                         \
    f32x4 acco[8];                                                                  \
    _Pragma("unroll") for (int i = 0; i < 8; ++i)                                   \
        acco[i] = (f32x4){0.f, 0.f, 0.f, 0.f};                                      \
    _Pragma("unroll") for (int qq = 0; qq < 4; ++qq) {                              \
      _Pragma("unroll") for (int ntl = 0; ntl < 4; ++ntl) {                         \
        int nt = qq * 4 + ntl;                                                      \
        unsigned int p0 = cvtpk(accs[nt][0] * inv_, accs[nt][1] * inv_);            \
        unsigned int p1 = cvtpk(accs[nt][2] * inv_, accs[nt][3] * inv_);            \
        int cw = 2 * ntl + (l4 >> 1);                                               \
        *(u32x2*)((char*)lpw + l15 * 128 + ((cw ^ (l15 & 7)) << 4) +                \
                  (l4 & 1) * 8) = (u32x2){p0, p1};                                  \
      }                                                                             \
      _Pragma("unroll") for (int ksl = 0; ksl < 2; ++ksl) {                         \
        bf16x8 pa = *(const bf16x8*)((char*)lpw + l15 * 128 +                       \
                                     (((4 * ksl + l4) ^ (l15 & 7)) << 4));          \
        int ksa = qq * 2 + ksl;                                                     \
        _Pragma("unroll") for (int ntv = 0; ntv < 8; ++ntv) {                       \
          bf16x8 bv = *(const bf16x8*)(&lvpt[(ntv * 16 + l15) * 256 +               \
                                             (((ksa * 4 + l4) ^ (l15 & 7)) << 3)]); \
          acco[ntv] = __builtin_amdgcn_mfma_f32_16x16x32_bf16(pa, bv, acco[ntv],    \
                                                              0, 0, 0);             \
        }                                                                           \
      }                                                                             \
    }                                                                               \
    float* ob_ = out + ((size_t)b * N_SEQ + slice * 512 + (TILE_I) * 128 +          \
                        w * 16) * D_HEAD;                                           \
    _Pragma("unroll") for (int ntv = 0; ntv < 8; ++ntv)                             \
        _Pragma("unroll") for (int r = 0; r < 4; ++r)                               \
            ob_[(size_t)(l4 * 4 + r) * D_HEAD + ntv * 16 + l15] = acco[ntv][r];     \
  } while (0)

  QLOAD(qA, 0);
  TILE_BODY(qA, qB, 0, 1);
  TILE_BODY(qB, qA, 1, 1);
  TILE_BODY(qA, qB, 2, 1);
  TILE_BODY(qB, qA, 3, 0);
#undef QLOAD
#undef TILE_BODY
}

// ---------------------------------------------------------------------------
extern "C" void kernel_launch(void* const* d_in, const int* in_sizes, int n_in,
                              void* d_out, int out_size, void* d_ws, size_t ws_size,
                              hipStream_t stream) {
  const float* Q  = (const float*)d_in[0];
  const float* K  = (const float*)d_in[1];
  const float* V  = (const float*)d_in[2];
  const float* EW = (const float*)d_in[3];
  const float* Eb = (const float*)d_in[4];
  const float* FW = (const float*)d_in[5];
  const float* Fb = (const float*)d_in[6];
  float* out = (float*)d_out;

  // d_out scratch (dead before attn writes): [0,4MB) wbf; [8MB,41.5MB) pws
  short* wbf = (short*)d_out;
  float* pws = (float*)d_out + 2097152;
  short* kpb = (short*)d_ws;
  short* vpt = (short*)((char*)d_ws + (size_t)32 * KP_DIM * D_HEAD * 2);

  conv_w_kernel<<<dim3(2048), dim3(256), 0, stream>>>(EW, FW, wbf);
  proj_partial_kernel<<<dim3(256), dim3(512), 0, stream>>>(K, V, wbf, pws);
  reduce_bias_kernel<<<dim3(128), dim3(256), 0, stream>>>(pws, Eb, Fb, kpb, vpt);
  attn_kernel<<<dim3(256), dim3(512), 0, stream>>>(Q, kpb, vpt, out);
}